// Round 10
// baseline (87.807 us; speedup 1.0000x reference)
//
#include <hip/hip_runtime.h>
#include <hip/hip_bf16.h>

typedef __attribute__((ext_vector_type(8))) short bf16x8;
typedef __attribute__((ext_vector_type(4))) float f32x4;
typedef __attribute__((ext_vector_type(4))) unsigned int u32x4;
typedef unsigned short u16;
typedef unsigned int u32;

static constexpr int KDIM  = 784;   // 28*28
static constexpr int KP    = 800;   // K padded (weff zero-pads k>=784 and n>=300)
static constexpr int NDIM  = 300;
static constexpr int NP    = 320;
static constexpr int DDIM  = 10;
static constexpr int BM    = 128;   // rows per block -> grid 512 = 2 blocks/CU
static constexpr int BK    = 32;
static constexpr int NSTEP = 25;
static constexpr int H1STR = 328;
static constexpr int NROW  = 65536;
static constexpr int NTHR  = 512;   // 8 waves: 2m x 4n, wave tile 64x80 (acc=80)
// LDS bytes: A fp32 2 x 16384 @ 0; B bf16 2 x 20480 @ 32768. Total 73728 (<80K).
static constexpr int ABYTES = 16384;
static constexpr int BBYTES = 20480;
static constexpr int BBASE  = 32768;

__device__ __forceinline__ u16 f2bf(float f) {
  unsigned u = __builtin_bit_cast(unsigned, f);
  u += 0x7fffu + ((u >> 16) & 1u);   // RNE
  return (u16)(u >> 16);
}
__device__ __forceinline__ u32 pk2(float a, float b) {
  u32 r;
  asm("v_cvt_pk_bf16_f32 %0, %1, %2" : "=v"(r) : "v"(a), "v"(b));
  return r;
}
__device__ __forceinline__ void gll16(const void* g, void* l) {
  __builtin_amdgcn_global_load_lds(
      (const __attribute__((address_space(1))) void*)g,
      (__attribute__((address_space(3))) void*)l, 16, 0, 0);
}

// ---- Kernel A: fold conv into first linear layer; weff_t[n][k] bf16, zero-padded ----
__global__ void build_weff(const float* __restrict__ cw,
                           const float* __restrict__ w1,
                           u16* __restrict__ weff) {
  int idx = blockIdx.x * 256 + threadIdx.x;
  if (idx >= NP * KP) return;
  int n = idx / KP;
  int k = idx - n * KP;
  float acc = 0.f;
  if (n < NDIM && k < KDIM) {
    int r = k / 28, c = k - (k / 28) * 28;
    #pragma unroll
    for (int dr = 0; dr < 3; ++dr) {
      int orr = r - dr;
      if ((unsigned)orr < 26u) {
        #pragma unroll
        for (int dc = 0; dc < 3; ++dc) {
          int oc = c - dc;
          if ((unsigned)oc < 26u)
            acc += cw[dr * 3 + dc] * w1[(orr * 26 + oc) * NDIM + n];
        }
      }
    }
  }
  weff[n * KP + k] = f2bf(acc);
}

// ---- Kernel B: out = relu(x @ Weff + b1) @ w2 + b2 ----
// 512 thr / 8 waves (2m x 4n); wave tile 64 rows x 80 cols -> acc = 4x5 frags
// = 80 AGPRs (total regs ~160/256: big headroom, no spill possible).
// Grid 512 = 2 blocks/CU: cross-block overlap hides each block's barrier
// drain (m97/m114 mechanism). A fp32 + B bf16 both via global_load_lds,
// 2-deep buffers staged 1 step ahead, one __syncthreads per step.
// XOR-swizzled chunk maps: global reads line-coalesced, LDS banks even.
__global__ void __launch_bounds__(NTHR, 2)
fused_mlp(const float* __restrict__ x, const float* __restrict__ b1,
          const float* __restrict__ w2, const float* __restrict__ b2,
          const u16* __restrict__ weff, float* __restrict__ out) {
  __shared__ __align__(16) u16 lds[36864];   // 73728 B -> 2 blocks/CU

  const int tid  = threadIdx.x;
  const int wv   = tid >> 6;
  const int lane = tid & 63;
  const int l16  = lane & 15;
  const int lhi  = lane >> 4;     // 0..3
  const int wm   = wv >> 2;       // 0..1 -> rows wm*64
  const int wn   = wv & 3;        // 0..3 -> cols wn*80
  const int bm   = blockIdx.x * BM;
  const int wvn  = wn * 80;

  // --- A staging (2 chunks/thread): slot s in [0,1024), row=s>>3 (8x16B/row),
  //     global chunk qg = (s&7) ^ (row&7)
  int aRow[2], aQg[2];
  #pragma unroll
  for (int it = 0; it < 2; ++it) {
    int s = tid + it * NTHR;
    aRow[it] = s >> 3;
    aQg[it]  = (s & 7) ^ (aRow[it] & 7);
  }
  // --- B staging (3 chunks/thread; slots 1024..1279 double-written benignly):
  //     slot s in [0,1280), row=s>>2, qg = (s&3) ^ (row&3)
  int bRow[3], bQg[3], bSlot[3];
  #pragma unroll
  for (int i = 0; i < 3; ++i) {
    int s = (i < 2) ? (tid + i * NTHR) : (1024 + (tid & 255));
    bSlot[i] = s;
    bRow[i]  = s >> 2;
    bQg[i]   = (s & 3) ^ (bRow[i] & 3);
  }

  auto stageA = [&](int bufi, int t) {
    char* base = (char*)lds + bufi * ABYTES;
    int k0 = t * BK;
    #pragma unroll
    for (int it = 0; it < 2; ++it) {
      int kof = k0 + aQg[it] * 4;
      if (kof >= KDIM) kof = aQg[it] * 4;   // t=24 pad chunks: finite garbage, B=0
      gll16(x + (size_t)(bm + aRow[it]) * KDIM + kof,
            base + (tid + it * NTHR) * 16);
    }
  };
  auto stageB = [&](int bufi, int t) {
    char* base = (char*)lds + BBASE + bufi * BBYTES;
    int k0 = t * BK;
    #pragma unroll
    for (int i = 0; i < 3; ++i)
      gll16(weff + (size_t)bRow[i] * KP + k0 + bQg[i] * 8, base + bSlot[i] * 16);
  };

  f32x4 acc[4][5];
  #pragma unroll
  for (int mi = 0; mi < 4; ++mi)
    #pragma unroll
    for (int ni = 0; ni < 5; ++ni)
      acc[mi][ni] = (f32x4){0.f, 0.f, 0.f, 0.f};

  auto compute = [&](int bufi) {
    const f32x4* Af = (const f32x4*)((char*)lds + bufi * ABYTES);
    const u16*   Bb = (const u16*)((char*)lds + BBASE + bufi * BBYTES);
    bf16x8 bfr[5];
    #pragma unroll
    for (int ni = 0; ni < 5; ++ni) {
      int n = wvn + ni * 16 + l16;
      int slot = n * 4 + (lhi ^ (n & 3));
      bfr[ni] = *reinterpret_cast<const bf16x8*>(Bb + slot * 8);
    }
    #pragma unroll
    for (int mi = 0; mi < 4; ++mi) {
      int R = wm * 64 + mi * 16 + l16;
      f32x4 a0 = Af[R * 8 + ((2 * lhi)     ^ (R & 7))];
      f32x4 a1 = Af[R * 8 + ((2 * lhi + 1) ^ (R & 7))];
      u32x4 amu = { pk2(a0[0], a0[1]), pk2(a0[2], a0[3]),
                    pk2(a1[0], a1[1]), pk2(a1[2], a1[3]) };
      bf16x8 am = __builtin_bit_cast(bf16x8, amu);
      #pragma unroll
      for (int ni = 0; ni < 5; ++ni)
        acc[mi][ni] = __builtin_amdgcn_mfma_f32_16x16x32_bf16(am, bfr[ni], acc[mi][ni], 0, 0, 0);
    }
  };

  // ---- prologue ----
  stageA(0, 0);
  stageB(0, 0);
  __syncthreads();

  // ---- main loop: 25 steps, dbuf, one __syncthreads per step ----
  for (int t = 0; t < NSTEP; ++t) {
    if (t + 1 < NSTEP) {
      stageB((t + 1) & 1, t + 1);
      stageA((t + 1) & 1, t + 1);
    }
    compute(t & 1);
    __syncthreads();   // drains this step's glls; other block computes meanwhile
  }

  // ---- epilogue: h1 = relu(acc + b1); out = h1 @ w2 + b2, 2 passes of 64 rows ----
  u16* H1  = lds;                  // [64][328] = 20992 u16
  u16* W2T = lds + 20992;          // [16][328] = 5248 u16 (ends 52480 B <= 73728)

  for (int i = tid; i < 16 * NP; i += NTHR) {
    int d = i / NP, n = i - (i / NP) * NP;
    float v = (d < DDIM && n < NDIM) ? w2[n * DDIM + d] : 0.f;
    W2T[d * H1STR + n] = f2bf(v);
  }
  float biasv[5];
  #pragma unroll
  for (int ni = 0; ni < 5; ++ni) {
    int col = wvn + ni * 16 + l16;
    biasv[ni] = (col < NDIM) ? b1[col] : 0.f;
  }

  #pragma unroll
  for (int p = 0; p < 2; ++p) {
    if (wm == p) {
      #pragma unroll
      for (int mi = 0; mi < 4; ++mi) {
        #pragma unroll
        for (int ni = 0; ni < 5; ++ni) {
          int col = wvn + ni * 16 + l16;
          int rb  = mi * 16 + lhi * 4;
          #pragma unroll
          for (int r = 0; r < 4; ++r) {
            float h = acc[mi][ni][r] + biasv[ni];
            H1[(rb + r) * H1STR + col] = f2bf(fmaxf(h, 0.f));
          }
        }
      }
    }
    __syncthreads();               // H1 (and W2T on p==0) visible
    if (wv < 4) {
      f32x4 a2c = (f32x4){0.f, 0.f, 0.f, 0.f};
      #pragma unroll
      for (int ks = 0; ks < NP / 32; ++ks) {
        bf16x8 a2 = *reinterpret_cast<const bf16x8*>(
            H1 + (wv * 16 + l16) * H1STR + ks * 32 + lhi * 8);
        bf16x8 bw = *reinterpret_cast<const bf16x8*>(
            W2T + l16 * H1STR + ks * 32 + lhi * 8);
        a2c = __builtin_amdgcn_mfma_f32_16x16x32_bf16(a2, bw, a2c, 0, 0, 0);
      }
      if (l16 < DDIM) {
        float bb = b2[l16];
        #pragma unroll
        for (int r = 0; r < 4; ++r) {
          int row = bm + p * 64 + wv * 16 + lhi * 4 + r;
          out[(size_t)row * DDIM + l16] = a2c[r] + bb;
        }
      }
    }
    __syncthreads();               // before next pass overwrites H1
  }
}

extern "C" void kernel_launch(void* const* d_in, const int* in_sizes, int n_in,
                              void* d_out, int out_size, void* d_ws, size_t ws_size,
                              hipStream_t stream) {
  const float* x  = (const float*)d_in[0];
  const float* cw = (const float*)d_in[1];
  const float* w1 = (const float*)d_in[2];
  const float* b1 = (const float*)d_in[3];
  const float* w2 = (const float*)d_in[4];
  const float* b2 = (const float*)d_in[5];
  float* out = (float*)d_out;
  u16* weff = (u16*)d_ws;   // 320*800*2 = 512000 bytes

  hipLaunchKernelGGL(build_weff, dim3((NP * KP + 255) / 256), dim3(256), 0, stream,
                     cw, w1, weff);
  hipLaunchKernelGGL(fused_mlp, dim3(NROW / BM), dim3(NTHR), 0, stream,
                     x, b1, w2, b2, weff, out);
}

// Round 11
// 77.640 us; speedup vs baseline: 1.1309x; 1.1309x over previous
//
#include <hip/hip_runtime.h>
#include <hip/hip_bf16.h>

typedef __attribute__((ext_vector_type(8))) short bf16x8;
typedef __attribute__((ext_vector_type(4))) float f32x4;
typedef __attribute__((ext_vector_type(4))) unsigned int u32x4;
typedef unsigned short u16;
typedef unsigned int u32;

static constexpr int KDIM  = 784;   // 28*28
static constexpr int KP    = 800;   // K padded (weff zero-pads k>=784 and n>=300)
static constexpr int NDIM  = 300;
static constexpr int NP    = 320;
static constexpr int DDIM  = 10;
static constexpr int BM    = 256;   // rows per block -> grid = 256 = 1 block/CU
static constexpr int BK    = 32;
static constexpr int NSTEP = 25;
static constexpr int H1STR = 328;
static constexpr int NROW  = 65536;
static constexpr int NTHR  = 512;   // 8 waves: 2m x 4n (wave tile 128x80)
// LDS: A fp32, 4 buffers x 32768 B = 131072 B total (1 block/CU).
static constexpr int ABYTES = 32768;

__device__ __forceinline__ u16 f2bf(float f) {
  unsigned u = __builtin_bit_cast(unsigned, f);
  u += 0x7fffu + ((u >> 16) & 1u);   // RNE
  return (u16)(u >> 16);
}
__device__ __forceinline__ u32 pk2(float a, float b) {
  u32 r;
  asm("v_cvt_pk_bf16_f32 %0, %1, %2" : "=v"(r) : "v"(a), "v"(b));
  return r;
}
__device__ __forceinline__ void gll16(const void* g, void* l) {
  __builtin_amdgcn_global_load_lds(
      (const __attribute__((address_space(1))) void*)g,
      (__attribute__((address_space(3))) void*)l, 16, 0, 0);
}

// ---- Kernel A: fold conv into first linear layer; weff_t[n][k] bf16, zero-padded ----
__global__ void build_weff(const float* __restrict__ cw,
                           const float* __restrict__ w1,
                           u16* __restrict__ weff) {
  int idx = blockIdx.x * 256 + threadIdx.x;
  if (idx >= NP * KP) return;
  int n = idx / KP;
  int k = idx - n * KP;
  float acc = 0.f;
  if (n < NDIM && k < KDIM) {
    int r = k / 28, c = k - (k / 28) * 28;
    #pragma unroll
    for (int dr = 0; dr < 3; ++dr) {
      int orr = r - dr;
      if ((unsigned)orr < 26u) {
        #pragma unroll
        for (int dc = 0; dc < 3; ++dc) {
          int oc = c - dc;
          if ((unsigned)oc < 26u)
            acc += cw[dr * 3 + dc] * w1[(orr * 26 + oc) * NDIM + n];
        }
      }
    }
  }
  weff[n * KP + k] = f2bf(acc);
}

// ---- Kernel B: out = relu(x @ Weff + b1) @ w2 + b2 ----
// 512 thr / 8 waves (2m x 4n); wave tile 128 rows x 80 cols (acc = 8x5 frags).
// Grid = 256 blocks = 1/CU.
// A (x fp32): global_load_lds, 4 buffers, staged 3 steps ahead; counted
//   vmcnt keeps 2 A-tiles in flight across every barrier (never drains).
// B (weff bf16, L2-hot): direct L2->VGPR at point of use, issued BEFORE the
//   A-glls each step so the MFMA's implicit B-wait is vmcnt(4) and leaves
//   the A lookahead untouched (in-order vmcnt queue).
__global__ void __launch_bounds__(NTHR, 2)
fused_mlp(const float* __restrict__ x, const float* __restrict__ b1,
          const float* __restrict__ w2, const float* __restrict__ b2,
          const u16* __restrict__ weff, float* __restrict__ out) {
  __shared__ __align__(16) u16 lds[65536];   // 131072 B -> 1 block/CU

  const int tid  = threadIdx.x;
  const int wv   = tid >> 6;
  const int lane = tid & 63;
  const int l16  = lane & 15;
  const int lhi  = lane >> 4;     // 0..3
  const int wm   = wv >> 2;       // 0..1 -> rows wm*128
  const int wn   = wv & 3;        // 0..3 -> cols wn*80
  const int bm   = blockIdx.x * BM;
  const int wvn  = wn * 80;

  // --- A staging (4 chunks/thread): slot s in [0,2048), row=s>>3 (8x16B/row),
  //     global chunk qg = (s&7) ^ (row&7)   (line-coalesced + bank-even)
  int aRow[4], aQg[4];
  #pragma unroll
  for (int it = 0; it < 4; ++it) {
    int s = tid + it * NTHR;
    aRow[it] = s >> 3;
    aQg[it]  = (s & 7) ^ (aRow[it] & 7);
  }

  auto stageA = [&](int bufi, int t) {
    char* base = (char*)lds + bufi * ABYTES;
    int k0 = (t < NSTEP) ? t * BK : 0;   // dummy stages keep vmcnt uniform
    #pragma unroll
    for (int it = 0; it < 4; ++it) {
      int kof = k0 + aQg[it] * 4;
      if (kof >= KDIM) kof = aQg[it] * 4;   // t=24 pad chunks: finite garbage, B=0
      gll16(x + (size_t)(bm + aRow[it]) * KDIM + kof,
            base + (tid + it * NTHR) * 16);
    }
  };

  // B fragment base offsets (u16 units into weff), one per ni
  int bOff[5];
  #pragma unroll
  for (int ni = 0; ni < 5; ++ni)
    bOff[ni] = (wvn + ni * 16 + l16) * KP + lhi * 8;

  f32x4 acc[8][5];
  #pragma unroll
  for (int mi = 0; mi < 8; ++mi)
    #pragma unroll
    for (int ni = 0; ni < 5; ++ni)
      acc[mi][ni] = (f32x4){0.f, 0.f, 0.f, 0.f};

  // ---- prologue: A(0),A(1),A(2) issued; drain A(0), keep A(1),A(2) ----
  stageA(0, 0);
  stageA(1, 1);
  stageA(2, 2);
  asm volatile("s_waitcnt vmcnt(8)" ::: "memory");
  __builtin_amdgcn_s_barrier();
  __builtin_amdgcn_sched_barrier(0);

  // ---- main loop: 25 steps, one barrier/step, A never drained below 2 tiles ----
  for (int t = 0; t < NSTEP; ++t) {
    // B(t): direct L2->reg, oldest VMEM of this step
    bf16x8 bfr[5];
    #pragma unroll
    for (int ni = 0; ni < 5; ++ni)
      bfr[ni] = *reinterpret_cast<const bf16x8*>(weff + bOff[ni] + t * BK);
    __builtin_amdgcn_sched_barrier(0);   // keep B issued before the A-glls
    stageA((t + 3) & 3, t + 3);          // 4 gll (dummy at t>=22 tail indices)
    __builtin_amdgcn_sched_barrier(0);

    const f32x4* Af = (const f32x4*)((char*)lds + (t & 3) * ABYTES);
    #pragma unroll
    for (int mi = 0; mi < 8; ++mi) {
      int R = wm * 128 + mi * 16 + l16;
      f32x4 a0 = Af[R * 8 + ((2 * lhi)     ^ (R & 7))];
      f32x4 a1 = Af[R * 8 + ((2 * lhi + 1) ^ (R & 7))];
      u32x4 amu = { pk2(a0[0], a0[1]), pk2(a0[2], a0[3]),
                    pk2(a1[0], a1[1]), pk2(a1[2], a1[3]) };
      bf16x8 am = __builtin_bit_cast(bf16x8, amu);
      #pragma unroll
      for (int ni = 0; ni < 5; ++ni)
        acc[mi][ni] = __builtin_amdgcn_mfma_f32_16x16x32_bf16(am, bfr[ni], acc[mi][ni], 0, 0, 0);
    }
    __builtin_amdgcn_sched_barrier(0);
    asm volatile("s_waitcnt vmcnt(4)" ::: "memory");  // keep A(t+3) in flight only
    __builtin_amdgcn_s_barrier();
    __builtin_amdgcn_sched_barrier(0);
  }
  __syncthreads();    // full drain (incl. dummy stages) before LDS overlay

  // ---- epilogue: h1 = relu(acc + b1); out = h1 @ w2 + b2, 4 passes of 64 rows ----
  u16* H1  = lds;                  // [64][328] = 20992 u16
  u16* W2T = lds + 20992;          // [16][328] = 5248 u16 (52480 B <= 131072)

  for (int i = tid; i < 16 * NP; i += NTHR) {
    int d = i / NP, n = i - (i / NP) * NP;
    float v = (d < DDIM && n < NDIM) ? w2[n * DDIM + d] : 0.f;
    W2T[d * H1STR + n] = f2bf(v);
  }
  float biasv[5];
  #pragma unroll
  for (int ni = 0; ni < 5; ++ni) {
    int col = wvn + ni * 16 + l16;
    biasv[ni] = (col < NDIM) ? b1[col] : 0.f;
  }

  #pragma unroll
  for (int p = 0; p < 4; ++p) {
    if (wm == (p >> 1)) {
      #pragma unroll
      for (int mj = 0; mj < 4; ++mj) {
        int mi = (p & 1) * 4 + mj;
        #pragma unroll
        for (int ni = 0; ni < 5; ++ni) {
          int col = wvn + ni * 16 + l16;
          int rb  = mj * 16 + lhi * 4;
          #pragma unroll
          for (int r = 0; r < 4; ++r) {
            float h = acc[mi][ni][r] + biasv[ni];
            H1[(rb + r) * H1STR + col] = f2bf(fmaxf(h, 0.f));
          }
        }
      }
    }
    __syncthreads();               // H1 (and W2T on p==0) visible
    if (wv < 4) {
      f32x4 a2c = (f32x4){0.f, 0.f, 0.f, 0.f};
      #pragma unroll
      for (int ks = 0; ks < NP / 32; ++ks) {
        bf16x8 a2 = *reinterpret_cast<const bf16x8*>(
            H1 + (wv * 16 + l16) * H1STR + ks * 32 + lhi * 8);
        bf16x8 bw = *reinterpret_cast<const bf16x8*>(
            W2T + l16 * H1STR + ks * 32 + lhi * 8);
        a2c = __builtin_amdgcn_mfma_f32_16x16x32_bf16(a2, bw, a2c, 0, 0, 0);
      }
      if (l16 < DDIM) {
        float bb = b2[l16];
        #pragma unroll
        for (int r = 0; r < 4; ++r) {
          int row = bm + p * 64 + wv * 16 + lhi * 4 + r;
          out[(size_t)row * DDIM + l16] = a2c[r] + bb;
        }
      }
    }
    __syncthreads();               // before next pass overwrites H1
  }
}

extern "C" void kernel_launch(void* const* d_in, const int* in_sizes, int n_in,
                              void* d_out, int out_size, void* d_ws, size_t ws_size,
                              hipStream_t stream) {
  const float* x  = (const float*)d_in[0];
  const float* cw = (const float*)d_in[1];
  const float* w1 = (const float*)d_in[2];
  const float* b1 = (const float*)d_in[3];
  const float* w2 = (const float*)d_in[4];
  const float* b2 = (const float*)d_in[5];
  float* out = (float*)d_out;
  u16* weff = (u16*)d_ws;   // 320*800*2 = 512000 bytes

  hipLaunchKernelGGL(build_weff, dim3((NP * KP + 255) / 256), dim3(256), 0, stream,
                     cw, w1, weff);
  hipLaunchKernelGGL(fused_mlp, dim3(NROW / BM), dim3(NTHR), 0, stream,
                     x, b1, w2, b2, weff, out);
}

// Round 12
// 69.620 us; speedup vs baseline: 1.2612x; 1.1152x over previous
//
#include <hip/hip_runtime.h>
#include <hip/hip_bf16.h>

typedef __attribute__((ext_vector_type(8))) short bf16x8;
typedef __attribute__((ext_vector_type(4))) float f32x4;
typedef __attribute__((ext_vector_type(4))) unsigned int u32x4;
typedef unsigned short u16;
typedef unsigned int u32;

static constexpr int KDIM  = 784;   // 28*28
static constexpr int KP    = 800;   // K padded (weff zero-pads k>=784 and n>=300)
static constexpr int NDIM  = 300;
static constexpr int NP    = 320;
static constexpr int DDIM  = 10;
static constexpr int BM    = 256;   // rows per block -> grid = 256 = 1 block/CU
static constexpr int BK    = 64;    // K per step: 12 full steps + 1 tail (K=32)
static constexpr int NFULL = 12;
static constexpr int H1STR = 328;
static constexpr int NROW  = 65536;
static constexpr int NTHR  = 512;   // 8 waves: 2m x 4n (wave tile 128x80)
// LDS (u16 units): A bf16 2 x 16384 @ 0; B bf16 2 x 20480 @ 32768. 147456 B.
static constexpr int AU    = 16384;
static constexpr int BBASEU= 32768;
static constexpr int BU    = 20480;

__device__ __forceinline__ u16 f2bf(float f) {
  unsigned u = __builtin_bit_cast(unsigned, f);
  u += 0x7fffu + ((u >> 16) & 1u);   // RNE
  return (u16)(u >> 16);
}
__device__ __forceinline__ u32 pk2(float a, float b) {
  u32 r;
  asm("v_cvt_pk_bf16_f32 %0, %1, %2" : "=v"(r) : "v"(a), "v"(b));
  return r;
}
__device__ __forceinline__ void gll16(const void* g, void* l) {
  __builtin_amdgcn_global_load_lds(
      (const __attribute__((address_space(1))) void*)g,
      (__attribute__((address_space(3))) void*)l, 16, 0, 0);
}

// ---- Kernel A: fold conv into first linear layer; weff_t[n][k] bf16, zero-padded ----
__global__ void build_weff(const float* __restrict__ cw,
                           const float* __restrict__ w1,
                           u16* __restrict__ weff) {
  int idx = blockIdx.x * 256 + threadIdx.x;
  if (idx >= NP * KP) return;
  int n = idx / KP;
  int k = idx - n * KP;
  float acc = 0.f;
  if (n < NDIM && k < KDIM) {
    int r = k / 28, c = k - (k / 28) * 28;
    #pragma unroll
    for (int dr = 0; dr < 3; ++dr) {
      int orr = r - dr;
      if ((unsigned)orr < 26u) {
        #pragma unroll
        for (int dc = 0; dc < 3; ++dc) {
          int oc = c - dc;
          if ((unsigned)oc < 26u)
            acc += cw[dr * 3 + dc] * w1[(orr * 26 + oc) * NDIM + n];
        }
      }
    }
  }
  weff[n * KP + k] = f2bf(acc);
}

// ---- Kernel B: out = relu(x @ Weff + b1) @ w2 + b2 ----
// 512 thr / 8 waves (2m x 4n); wave tile 128 x 80 (acc = 8x5 frags = 160).
// Grid = 256 = 1 block/CU. BK=64: half the barriers of r9.
// A: global->reg (pinned early by sched_barrier) -> pk2 -> ds_write as BF16
//    (halves A LDS bytes and fragment-read count vs fp32 staging).
// B: global_load_lds 2-deep, 1 step ahead (L2-resident weff).
// Counted vmcnt: after compute kk=0, vmcnt(5) drains only the 8 A-loads;
// B glls stay in flight until the pre-barrier vmcnt(0) (landed long before).
__global__ void __launch_bounds__(NTHR, 2)
fused_mlp(const float* __restrict__ x, const float* __restrict__ b1,
          const float* __restrict__ w2, const float* __restrict__ b2,
          const u16* __restrict__ weff, float* __restrict__ out) {
  __shared__ __align__(16) u16 lds[73728];   // 147456 B -> 1 block/CU

  const int tid  = threadIdx.x;
  const int wv   = tid >> 6;
  const int lane = tid & 63;
  const int l16  = lane & 15;
  const int lhi  = lane >> 4;     // 0..3
  const int wm   = wv >> 2;       // 0..1 -> rows wm*128
  const int wn   = wv & 3;        // 0..3 -> cols wn*80
  const int bm   = blockIdx.x * BM;
  const int wvn  = wn * 80;

  // A staging ids: pair p = tid + j*512 in [0,2048); row R=p>>3; pp=p&7;
  // global k-octet og = pp ^ (R&7)  (line-dense loads, slot p stores oct og)
  int aR[4], aOg[4];
  #pragma unroll
  for (int j = 0; j < 4; ++j) {
    int p = tid + j * NTHR;
    aR[j]  = p >> 3;
    aOg[j] = (p & 7) ^ (aR[j] & 7);
  }
  // B staging ids: slot s = tid + i*512 in [0,2560); row n=s>>3; o=s&7;
  // global oct og = o ^ (n&7)
  int bN[5], bOg[5];
  #pragma unroll
  for (int i = 0; i < 5; ++i) {
    int s = tid + i * NTHR;
    bN[i]  = s >> 3;
    bOg[i] = (s & 7) ^ (bN[i] & 7);
  }

  f32x4 av[4][2];   // fp32 staging regs for one A step (32 VGPR)

  auto aload = [&](int t) {
    int k0 = t * BK;
    #pragma unroll
    for (int j = 0; j < 4; ++j) {
      int k = k0 + aOg[j] * 8;
      if (k + 8 > KDIM) k = k0;      // tail (t=12, og>=2): valid-range garbage; B zero-pad kills it
      const float* g = x + (size_t)(bm + aR[j]) * KDIM + k;
      av[j][0] = *reinterpret_cast<const f32x4*>(g);
      av[j][1] = *reinterpret_cast<const f32x4*>(g + 4);
    }
  };
  auto cvtwrite = [&](int t) {
    u16* Ab = lds + (t & 1) * AU;
    #pragma unroll
    for (int j = 0; j < 4; ++j) {
      int p = tid + j * NTHR;
      u32x4 q = { pk2(av[j][0][0], av[j][0][1]), pk2(av[j][0][2], av[j][0][3]),
                  pk2(av[j][1][0], av[j][1][1]), pk2(av[j][1][2], av[j][1][3]) };
      *reinterpret_cast<u32x4*>(Ab + p * 8) = q;   // slot p, 16 B
    }
  };
  auto stageB = [&](int t) {
    char* base = (char*)(lds + BBASEU + (t & 1) * BU);
    int k0 = t * BK;
    #pragma unroll
    for (int i = 0; i < 5; ++i) {
      int k = k0 + bOg[i] * 8;
      if (k + 8 > KP) k = k0;        // tail (t=12, og>=4): valid-range garbage, never read
      gll16(weff + (size_t)bN[i] * KP + k, base + (tid + i * NTHR) * 16);
    }
  };

  f32x4 acc[8][5];
  #pragma unroll
  for (int mi = 0; mi < 8; ++mi)
    #pragma unroll
    for (int ni = 0; ni < 5; ++ni)
      acc[mi][ni] = (f32x4){0.f, 0.f, 0.f, 0.f};

  auto compute = [&](int t, int kk) {
    const u16* Ab = lds + (t & 1) * AU;
    const u16* Bb = lds + BBASEU + (t & 1) * BU;
    const int o = kk * 4 + lhi;
    bf16x8 bfr[5];
    #pragma unroll
    for (int ni = 0; ni < 5; ++ni) {
      int n = wvn + ni * 16 + l16;
      bfr[ni] = *reinterpret_cast<const bf16x8*>(Bb + (n * 8 + (o ^ (n & 7))) * 8);
    }
    #pragma unroll
    for (int mi = 0; mi < 8; ++mi) {
      int R = wm * 128 + mi * 16 + l16;
      bf16x8 am = *reinterpret_cast<const bf16x8*>(Ab + (R * 8 + (o ^ (R & 7))) * 8);
      #pragma unroll
      for (int ni = 0; ni < 5; ++ni)
        acc[mi][ni] = __builtin_amdgcn_mfma_f32_16x16x32_bf16(am, bfr[ni], acc[mi][ni], 0, 0, 0);
    }
  };

  // ---- prologue: stage A(0), B(0) ----
  aload(0);
  __builtin_amdgcn_sched_barrier(0);
  stageB(0);
  __builtin_amdgcn_sched_barrier(0);
  asm volatile("s_waitcnt vmcnt(5)" ::: "memory");   // A loads done; B glls in flight
  cvtwrite(0);
  asm volatile("s_waitcnt vmcnt(0) lgkmcnt(0)" ::: "memory");
  __builtin_amdgcn_s_barrier();
  __builtin_amdgcn_sched_barrier(0);

  // ---- main loop: 12 steps of K=64, one barrier per step ----
  for (int t = 0; t < NFULL; ++t) {
    aload(t + 1);                       // 8 global dwordx4 (issued first)
    __builtin_amdgcn_sched_barrier(0);
    stageB(t + 1);                      // 5 gll
    __builtin_amdgcn_sched_barrier(0);
    compute(t, 0);                      // 40 MFMA
    __builtin_amdgcn_sched_barrier(0);
    asm volatile("s_waitcnt vmcnt(5)" ::: "memory");  // drain A loads, keep B glls
    cvtwrite(t + 1);                    // 16 pk2 + 4 ds_write_b128
    __builtin_amdgcn_sched_barrier(0);
    compute(t, 1);                      // 40 MFMA
    __builtin_amdgcn_sched_barrier(0);
    asm volatile("s_waitcnt vmcnt(0) lgkmcnt(0)" ::: "memory");
    __builtin_amdgcn_s_barrier();
    __builtin_amdgcn_sched_barrier(0);
  }
  compute(NFULL, 0);    // tail: k = 768..799 (zero-padded past 784)
  __syncthreads();

  // ---- epilogue: h1 = relu(acc + b1); out = h1 @ w2 + b2, 4 passes of 64 rows ----
  u16* H1  = lds;                  // [64][328] = 20992 u16
  u16* W2T = lds + 20992;          // [16][328] = 5248 u16

  for (int i = tid; i < 16 * NP; i += NTHR) {
    int d = i / NP, n = i - (i / NP) * NP;
    float v = (d < DDIM && n < NDIM) ? w2[n * DDIM + d] : 0.f;
    W2T[d * H1STR + n] = f2bf(v);
  }
  float biasv[5];
  #pragma unroll
  for (int ni = 0; ni < 5; ++ni) {
    int col = wvn + ni * 16 + l16;
    biasv[ni] = (col < NDIM) ? b1[col] : 0.f;
  }

  #pragma unroll
  for (int p = 0; p < 4; ++p) {
    if (wm == (p >> 1)) {
      #pragma unroll
      for (int mj = 0; mj < 4; ++mj) {
        int mi = (p & 1) * 4 + mj;
        #pragma unroll
        for (int ni = 0; ni < 5; ++ni) {
          int col = wvn + ni * 16 + l16;
          int rb  = mj * 16 + lhi * 4;
          #pragma unroll
          for (int r = 0; r < 4; ++r) {
            float h = acc[mi][ni][r] + biasv[ni];
            H1[(rb + r) * H1STR + col] = f2bf(fmaxf(h, 0.f));
          }
        }
      }
    }
    __syncthreads();               // H1 (and W2T on p==0) visible
    if (wv < 4) {
      f32x4 a2c = (f32x4){0.f, 0.f, 0.f, 0.f};
      #pragma unroll
      for (int ks = 0; ks < NP / 32; ++ks) {
        bf16x8 a2 = *reinterpret_cast<const bf16x8*>(
            H1 + (wv * 16 + l16) * H1STR + ks * 32 + lhi * 8);
        bf16x8 bw = *reinterpret_cast<const bf16x8*>(
            W2T + l16 * H1STR + ks * 32 + lhi * 8);
        a2c = __builtin_amdgcn_mfma_f32_16x16x32_bf16(a2, bw, a2c, 0, 0, 0);
      }
      if (l16 < DDIM) {
        float bb = b2[l16];
        #pragma unroll
        for (int r = 0; r < 4; ++r) {
          int row = bm + p * 64 + wv * 16 + lhi * 4 + r;
          out[(size_t)row * DDIM + l16] = a2c[r] + bb;
        }
      }
    }
    __syncthreads();               // before next pass overwrites H1
  }
}

extern "C" void kernel_launch(void* const* d_in, const int* in_sizes, int n_in,
                              void* d_out, int out_size, void* d_ws, size_t ws_size,
                              hipStream_t stream) {
  const float* x  = (const float*)d_in[0];
  const float* cw = (const float*)d_in[1];
  const float* w1 = (const float*)d_in[2];
  const float* b1 = (const float*)d_in[3];
  const float* w2 = (const float*)d_in[4];
  const float* b2 = (const float*)d_in[5];
  float* out = (float*)d_out;
  u16* weff = (u16*)d_ws;   // 320*800*2 = 512000 bytes

  hipLaunchKernelGGL(build_weff, dim3((NP * KP + 255) / 256), dim3(256), 0, stream,
                     cw, w1, weff);
  hipLaunchKernelGGL(fused_mlp, dim3(NROW / BM), dim3(NTHR), 0, stream,
                     x, b1, w2, b2, weff, out);
}